// Round 2
// baseline (526.273 us; speedup 1.0000x reference)
//
#include <hip/hip_runtime.h>

#define ALPHA 0.2f
#define LDA 136   // LDS row stride in shorts (272 B: aligned, conflict-balanced)

typedef short bf16x8 __attribute__((ext_vector_type(8)));
typedef float f32x4  __attribute__((ext_vector_type(4)));

static __device__ __forceinline__ float bf2f(unsigned short u) {
    union { unsigned int i; float f; } v; v.i = ((unsigned int)u) << 16; return v.f;
}
static __device__ __forceinline__ unsigned short f2bf(float f) {
    union { float f; unsigned int i; } v; v.f = f;
    unsigned int x = v.i;
    return (unsigned short)((x + 0x7fffu + ((x >> 16) & 1u)) >> 16);  // RNE
}
// bf16 pair unpack: low short = <<16, high short = mask (1 VALU op each)
static __device__ __forceinline__ float bflo(int u) {
    union { unsigned int i; float f; } v; v.i = ((unsigned int)u) << 16; return v.f;
}
static __device__ __forceinline__ float bfhi(int u) {
    union { unsigned int i; float f; } v; v.i = ((unsigned int)u) & 0xffff0000u; return v.f;
}
// 8-channel FMA from one dwordx4 of bf16
static __device__ __forceinline__ void acc8(float* a, const int4 hv, const float w) {
    a[0] = fmaf(w, bflo(hv.x), a[0]); a[1] = fmaf(w, bfhi(hv.x), a[1]);
    a[2] = fmaf(w, bflo(hv.y), a[2]); a[3] = fmaf(w, bfhi(hv.y), a[3]);
    a[4] = fmaf(w, bflo(hv.z), a[4]); a[5] = fmaf(w, bfhi(hv.z), a[5]);
    a[6] = fmaf(w, bflo(hv.w), a[6]); a[7] = fmaf(w, bfhi(hv.w), a[7]);
}

// W in MFMA-FRAGMENT order: unit u16b[(t*4+ks)*64 + lane] = 8 bf16 of
// wT row (t*16 + m), cols (ks*32 + q*8 .. +7), lane = q*16 + m.
// GEMM B-loads become perfectly coalesced 1KB/instr global reads (L2-hot),
// eliminating the Bs LDS tile entirely.
__global__ __launch_bounds__(64)
void prep_wT_frag(const float* __restrict__ w1, const float* __restrict__ w2,
                  unsigned short* __restrict__ wT1f, unsigned short* __restrict__ wT2f)
{
    const int b = blockIdx.x;          // 0..63
    const float* w = (b >> 5) ? w2 : w1;
    unsigned short* wf = (b >> 5) ? wT2f : wT1f;
    const int u = b & 31;              // t*4 + ks
    const int t = u >> 2, ks = u & 3;
    const int lane = threadIdx.x;      // 0..63
    const int m = lane & 15, q = lane >> 4;
    const int c  = t * 16 + m;         // output column
    const int k0 = ks * 32 + q * 8;    // input-dim offset

    ushort4 u0, u1;
    u0.x = f2bf(w[(k0 + 0) * 128 + c]); u0.y = f2bf(w[(k0 + 1) * 128 + c]);
    u0.z = f2bf(w[(k0 + 2) * 128 + c]); u0.w = f2bf(w[(k0 + 3) * 128 + c]);
    u1.x = f2bf(w[(k0 + 4) * 128 + c]); u1.y = f2bf(w[(k0 + 5) * 128 + c]);
    u1.z = f2bf(w[(k0 + 6) * 128 + c]); u1.w = f2bf(w[(k0 + 7) * 128 + c]);
    *(ushort4*)&wf[(u * 64 + lane) * 8]     = u0;
    *(ushort4*)&wf[(u * 64 + lane) * 8 + 4] = u1;
}

// Layer-1 GEMM + fused score dots. B direct-from-global (fragment layout):
// LDS 35.8 KB -> 18.4 KB, 6 blocks/CU.
__global__ __launch_bounds__(256, 6)
void gemm_score_mfma(const float* __restrict__ src,      // x, fp32
                     const unsigned short* __restrict__ wTf,
                     const float* __restrict__ a_in,
                     const float* __restrict__ a_out,
                     unsigned short* __restrict__ hid,
                     float* __restrict__ s_in,
                     float* __restrict__ s_out,
                     int n)
{
    __shared__ short Es[64 * LDA];    // epilogue staging only
    __shared__ float aS[2][128];

    const int tid  = threadIdx.x;
    const int lane = tid & 63;
    const int wv   = tid >> 6;
    const int m    = lane & 15;
    const int q    = lane >> 4;
    const int rbase = blockIdx.x * 64;
    const int row   = rbase + wv * 16 + m;
    const bool rok  = (row < n);

    if (tid < 128) { aS[0][tid] = a_in[tid]; aS[1][tid] = a_out[tid]; }

    bf16x8 aF[4];
    {
        const float* p = &src[(size_t)row * 128 + q * 8];
        #pragma unroll
        for (int ks = 0; ks < 4; ks++) {
            if (rok) {
                float4 v0 = *(const float4*)(p + ks * 32);
                float4 v1 = *(const float4*)(p + ks * 32 + 4);
                bf16x8 a;
                a[0] = (short)f2bf(v0.x); a[1] = (short)f2bf(v0.y);
                a[2] = (short)f2bf(v0.z); a[3] = (short)f2bf(v0.w);
                a[4] = (short)f2bf(v1.x); a[5] = (short)f2bf(v1.y);
                a[6] = (short)f2bf(v1.z); a[7] = (short)f2bf(v1.w);
                aF[ks] = a;
            } else aF[ks] = (bf16x8){0,0,0,0,0,0,0,0};
        }
    }
    __syncthreads();                  // aS visible to all waves

    f32x4 acc[8];
    #pragma unroll
    for (int t = 0; t < 8; t++) acc[t] = (f32x4){0.f, 0.f, 0.f, 0.f};

    const bf16x8* Bf = (const bf16x8*)wTf;
    #pragma unroll
    for (int ks = 0; ks < 4; ks++) {
        #pragma unroll
        for (int t = 0; t < 8; t++) {
            bf16x8 bF = Bf[(t * 4 + ks) * 64 + lane];
            acc[t] = __builtin_amdgcn_mfma_f32_16x16x32_bf16(aF[ks], bF, acc[t], 0, 0, 0);
        }
    }

    float pin[4] = {0.f, 0.f, 0.f, 0.f}, pout[4] = {0.f, 0.f, 0.f, 0.f};
    #pragma unroll
    for (int t = 0; t < 8; t++) {
        float ai = aS[0][t * 16 + m];
        float ao = aS[1][t * 16 + m];
        #pragma unroll
        for (int r = 0; r < 4; r++) {
            pin[r]  += acc[t][r] * ai;
            pout[r] += acc[t][r] * ao;
        }
    }
    #pragma unroll
    for (int msk = 8; msk >= 1; msk >>= 1) {
        #pragma unroll
        for (int r = 0; r < 4; r++) {
            pin[r]  += __shfl_xor(pin[r],  msk);
            pout[r] += __shfl_xor(pout[r], msk);
        }
    }
    if (m == 0) {
        #pragma unroll
        for (int r = 0; r < 4; r++) {
            int g = rbase + wv * 16 + q * 4 + r;
            if (g < n) { s_in[g] = pin[r]; s_out[g] = pout[r]; }
        }
    }

    // epilogue: per-wave rows, no pre-barrier needed (Es untouched so far)
    #pragma unroll
    for (int t = 0; t < 8; t++)
        #pragma unroll
        for (int r = 0; r < 4; r++)
            Es[(wv * 16 + q * 4 + r) * LDA + t * 16 + m] = (short)f2bf(acc[t][r]);
    __syncthreads();
    #pragma unroll
    for (int i = 0; i < 4; i++) {
        int e = tid + i * 256;
        int r = e >> 4, j = (e & 15) * 8;
        int gr = rbase + r;
        if (gr < n) {
            int4 v = *(const int4*)&Es[r * LDA + j];
            *(int4*)&hid[(size_t)gr * 128 + j] = v;
        }
    }
}

// FUSED aggregate(layer1) + GEMM(layer2). B direct-from-global (fragment
// layout): no Bs tile, no restage barriers. LDS 18.4 KB -> 8 blocks/CU
// (was 4): 2x resident waves for the latency-bound phase-A gather.
__global__ __launch_bounds__(256, 8)
void fused_agg_gemm(const unsigned short* __restrict__ hid1,
                    const float* __restrict__ s_in1,
                    const float* __restrict__ s_out1,
                    const int* __restrict__ dst,
                    const float* __restrict__ adj,
                    const float* __restrict__ bias1,
                    const unsigned short* __restrict__ wT2f,
                    const float* __restrict__ a_in2,
                    const float* __restrict__ a_out2,
                    unsigned short* __restrict__ hid2,
                    float* __restrict__ s_in2,
                    float* __restrict__ s_out2,
                    int n)
{
    __shared__ short As[64 * LDA];    // pair table -> h1' tile -> epilogue
    __shared__ float aS[2][128];

    const int tid  = threadIdx.x;
    const int lane = tid & 63;
    const int wv   = tid >> 6;
    const int rbase = blockIdx.x * 64;

    if (tid < 128) { aS[0][tid] = a_in2[tid]; aS[1][tid] = a_out2[tid]; }

    // ---- Phase A1: softmax, 4 lanes/node ----
    const int jn  = lane >> 2;
    const int kq  = lane & 3;
    const int node = rbase + wv * 16 + jn;
    const bool nok = (node < n);

    int4   dk4 = make_int4(0, 0, 0, 0);
    float4 av4 = make_float4(0.f, 0.f, 0.f, 0.f);
    float  si  = 0.f;
    if (nok) {
        dk4 = *(const int4*)&dst[node * 16 + kq * 4];
        av4 = *(const float4*)&adj[node * 16 + kq * 4];
        si  = s_in1[node];
    }
    float e0 = si + s_out1[dk4.x], e1 = si + s_out1[dk4.y];
    float e2 = si + s_out1[dk4.z], e3 = si + s_out1[dk4.w];
    e0 = (e0 > 0.f) ? e0 : ALPHA * e0;  e1 = (e1 > 0.f) ? e1 : ALPHA * e1;
    e2 = (e2 > 0.f) ? e2 : ALPHA * e2;  e3 = (e3 > 0.f) ? e3 : ALPHA * e3;
    float mx = fmaxf(fmaxf(e0, e1), fmaxf(e2, e3));
    mx = fmaxf(mx, __shfl_xor(mx, 1));
    mx = fmaxf(mx, __shfl_xor(mx, 2));
    float p0 = __expf(e0 - mx), p1 = __expf(e1 - mx);
    float p2 = __expf(e2 - mx), p3 = __expf(e3 - mx);
    float sm = p0 + p1 + p2 + p3;
    sm += __shfl_xor(sm, 1);
    sm += __shfl_xor(sm, 2);
    const float inv = __frcp_rn(sm);

    // pair table {dk, wk} into bytes [0,128) of this node's As row
    {
        short* rowp = &As[(wv * 16 + jn) * LDA];
        int4 pa = make_int4(dk4.x, __float_as_int(av4.x * p0 * inv),
                            dk4.y, __float_as_int(av4.y * p1 * inv));
        int4 pb = make_int4(dk4.z, __float_as_int(av4.z * p2 * inv),
                            dk4.w, __float_as_int(av4.w * p3 * inv));
        *(int4*)(rowp + kq * 16)     = pa;   // pairs kq*4, kq*4+1
        *(int4*)(rowp + kq * 16 + 8) = pb;   // pairs kq*4+2, kq*4+3
    }

    // ---- Phase A2: gather, 16-lane group per node, dwordx4 loads ----
    const int m = lane & 15;
    const int q = lane >> 4;
    {
        const float4 bb0 = *(const float4*)&bias1[m * 8];
        const float4 bb1 = *(const float4*)&bias1[m * 8 + 4];
        #pragma unroll
        for (int jj = 0; jj < 4; jj++) {
            const int rloc = wv * 16 + jj * 4 + q;   // each (jj,q) owns one row
            const short* trow = &As[rloc * LDA];
            float acc[8] = {0.f, 0.f, 0.f, 0.f, 0.f, 0.f, 0.f, 0.f};
            #pragma unroll
            for (int k2 = 0; k2 < 8; k2++) {         // 2 neighbors per iter
                const int4 pp  = *(const int4*)(trow + k2 * 8);   // uniform bcast
                const int4 hv0 = *(const int4*)&hid1[((size_t)(unsigned)pp.x << 7) + (m << 3)];
                const int4 hv1 = *(const int4*)&hid1[((size_t)(unsigned)pp.z << 7) + (m << 3)];
                acc8(acc, hv0, __int_as_float(pp.y));
                acc8(acc, hv1, __int_as_float(pp.w));
            }
            const float r0 = fmaxf(acc[0] + bb0.x, 0.f);
            const float r1 = fmaxf(acc[1] + bb0.y, 0.f);
            const float r2 = fmaxf(acc[2] + bb0.z, 0.f);
            const float r3 = fmaxf(acc[3] + bb0.w, 0.f);
            const float r4 = fmaxf(acc[4] + bb1.x, 0.f);
            const float r5 = fmaxf(acc[5] + bb1.y, 0.f);
            const float r6 = fmaxf(acc[6] + bb1.z, 0.f);
            const float r7 = fmaxf(acc[7] + bb1.w, 0.f);
            int4 ov;
            ov.x = (int)f2bf(r0) | ((int)f2bf(r1) << 16);
            ov.y = (int)f2bf(r2) | ((int)f2bf(r3) << 16);
            ov.z = (int)f2bf(r4) | ((int)f2bf(r5) << 16);
            ov.w = (int)f2bf(r6) | ((int)f2bf(r7) << 16);
            *(int4*)&As[rloc * LDA + m * 8] = ov;    // overwrites own table: safe
        }
    }
    __syncthreads();    // aS visible; As tile complete (A-frags read next)

    // ---- Phase B: GEMM from As x global-fragment B, single pass ----
    bf16x8 aF[4];
    {
        const short* Abase = &As[(wv * 16 + m) * LDA + q * 8];
        #pragma unroll
        for (int ks = 0; ks < 4; ks++)
            aF[ks] = *(const bf16x8*)(Abase + ks * 32);
    }

    f32x4 acc[8];
    #pragma unroll
    for (int t = 0; t < 8; t++) acc[t] = (f32x4){0.f, 0.f, 0.f, 0.f};

    const bf16x8* Bf = (const bf16x8*)wT2f;
    #pragma unroll
    for (int ks = 0; ks < 4; ks++) {
        #pragma unroll
        for (int t = 0; t < 8; t++) {
            bf16x8 bF = Bf[(t * 4 + ks) * 64 + lane];
            acc[t] = __builtin_amdgcn_mfma_f32_16x16x32_bf16(aF[ks], bF, acc[t], 0, 0, 0);
        }
    }

    // fused layer-2 score dots
    float pin[4] = {0.f, 0.f, 0.f, 0.f}, pout[4] = {0.f, 0.f, 0.f, 0.f};
    #pragma unroll
    for (int t = 0; t < 8; t++) {
        float ai = aS[0][t * 16 + m];
        float ao = aS[1][t * 16 + m];
        #pragma unroll
        for (int r = 0; r < 4; r++) {
            pin[r]  += acc[t][r] * ai;
            pout[r] += acc[t][r] * ao;
        }
    }
    #pragma unroll
    for (int msk = 8; msk >= 1; msk >>= 1) {
        #pragma unroll
        for (int r = 0; r < 4; r++) {
            pin[r]  += __shfl_xor(pin[r],  msk);
            pout[r] += __shfl_xor(pout[r], msk);
        }
    }
    if (m == 0) {
        #pragma unroll
        for (int r = 0; r < 4; r++) {
            int g = rbase + wv * 16 + q * 4 + r;
            if (g < n) { s_in2[g] = pin[r]; s_out2[g] = pout[r]; }
        }
    }

    // epilogue: own-wave rows of As (aF hoisted -> As dead for this wave)
    short* Eo = As;
    #pragma unroll
    for (int t = 0; t < 8; t++)
        #pragma unroll
        for (int r = 0; r < 4; r++)
            Eo[(wv * 16 + q * 4 + r) * LDA + t * 16 + m] = (short)f2bf(acc[t][r]);
    __syncthreads();
    #pragma unroll
    for (int i = 0; i < 4; i++) {
        int e = tid + i * 256;
        int r = e >> 4, j = (e & 15) * 8;
        int gr = rbase + r;
        if (gr < n) {
            int4 v = *(const int4*)&Eo[r * LDA + j];
            *(int4*)&hid2[(size_t)gr * 128 + j] = v;
        }
    }
}

// Final aggregate: 64 nodes/block, 16 nodes/wave, 4-lane softmax + LDS pair
// table, dwordx4 gather. min-8-blocks residency: the latency-bound gather
// keeps ~all 6.1 blocks/CU of total work resident simultaneously.
__global__ __launch_bounds__(256, 8)
void gat_aggregate_final(const unsigned short* __restrict__ hid,
                         const float* __restrict__ s_in,
                         const float* __restrict__ s_out,
                         const int* __restrict__ dst,
                         const float* __restrict__ adj,
                         const float* __restrict__ bias,
                         float* __restrict__ out,
                         int n)
{
    __shared__ __align__(16) int2 tbl[64][18];   // 9216 B; stride 144 B

    const int tid  = threadIdx.x;
    const int lane = tid & 63;
    const int wv   = tid >> 6;
    const int rbase = blockIdx.x * 64;

    const int jn  = lane >> 2;
    const int kq  = lane & 3;
    const int node = rbase + wv * 16 + jn;
    const bool nok = (node < n);

    int4   dk4 = make_int4(0, 0, 0, 0);
    float4 av4 = make_float4(0.f, 0.f, 0.f, 0.f);
    float  si  = 0.f;
    if (nok) {
        dk4 = *(const int4*)&dst[node * 16 + kq * 4];
        av4 = *(const float4*)&adj[node * 16 + kq * 4];
        si  = s_in[node];
    }
    float e0 = si + s_out[dk4.x], e1 = si + s_out[dk4.y];
    float e2 = si + s_out[dk4.z], e3 = si + s_out[dk4.w];
    e0 = (e0 > 0.f) ? e0 : ALPHA * e0;  e1 = (e1 > 0.f) ? e1 : ALPHA * e1;
    e2 = (e2 > 0.f) ? e2 : ALPHA * e2;  e3 = (e3 > 0.f) ? e3 : ALPHA * e3;
    float mx = fmaxf(fmaxf(e0, e1), fmaxf(e2, e3));
    mx = fmaxf(mx, __shfl_xor(mx, 1));
    mx = fmaxf(mx, __shfl_xor(mx, 2));
    float p0 = __expf(e0 - mx), p1 = __expf(e1 - mx);
    float p2 = __expf(e2 - mx), p3 = __expf(e3 - mx);
    float sm = p0 + p1 + p2 + p3;
    sm += __shfl_xor(sm, 1);
    sm += __shfl_xor(sm, 2);
    const float inv = __frcp_rn(sm);

    {
        int4 pa = make_int4(dk4.x, __float_as_int(av4.x * p0 * inv),
                            dk4.y, __float_as_int(av4.y * p1 * inv));
        int4 pb = make_int4(dk4.z, __float_as_int(av4.z * p2 * inv),
                            dk4.w, __float_as_int(av4.w * p3 * inv));
        *(int4*)&tbl[wv * 16 + jn][kq * 4]     = pa;
        *(int4*)&tbl[wv * 16 + jn][kq * 4 + 2] = pb;
    }
    // table rows [wv*16, wv*16+16) written and read by the same wave: no barrier

    const int m = lane & 15;
    const int q = lane >> 4;
    const float4 bb0 = *(const float4*)&bias[m * 8];
    const float4 bb1 = *(const float4*)&bias[m * 8 + 4];

    #pragma unroll
    for (int jj = 0; jj < 4; jj++) {
        const int rl = wv * 16 + jj * 4 + q;
        const int nodeg = rbase + rl;
        float acc[8] = {0.f, 0.f, 0.f, 0.f, 0.f, 0.f, 0.f, 0.f};
        #pragma unroll
        for (int k2 = 0; k2 < 8; k2++) {
            const int4 pp  = *(const int4*)&tbl[rl][k2 * 2];      // uniform bcast
            const int4 hv0 = *(const int4*)&hid[((size_t)(unsigned)pp.x << 7) + (m << 3)];
            const int4 hv1 = *(const int4*)&hid[((size_t)(unsigned)pp.z << 7) + (m << 3)];
            acc8(acc, hv0, __int_as_float(pp.y));
            acc8(acc, hv1, __int_as_float(pp.w));
        }
        if (nodeg < n) {
            float4 o0, o1;
            o0.x = fmaxf(acc[0] + bb0.x, 0.f);
            o0.y = fmaxf(acc[1] + bb0.y, 0.f);
            o0.z = fmaxf(acc[2] + bb0.z, 0.f);
            o0.w = fmaxf(acc[3] + bb0.w, 0.f);
            o1.x = fmaxf(acc[4] + bb1.x, 0.f);
            o1.y = fmaxf(acc[5] + bb1.y, 0.f);
            o1.z = fmaxf(acc[6] + bb1.z, 0.f);
            o1.w = fmaxf(acc[7] + bb1.w, 0.f);
            float* op = &out[(size_t)nodeg * 128 + m * 8];
            *(float4*)op       = o0;
            *(float4*)(op + 4) = o1;
        }
    }
}

extern "C" void kernel_launch(void* const* d_in, const int* in_sizes, int n_in,
                              void* d_out, int out_size, void* d_ws, size_t ws_size,
                              hipStream_t stream)
{
    const float* x      = (const float*)d_in[0];
    const int*   dst    = (const int*)d_in[1];
    const float* adj    = (const float*)d_in[2];
    const float* w1     = (const float*)d_in[3];
    const float* a_in1  = (const float*)d_in[4];
    const float* a_out1 = (const float*)d_in[5];
    const float* b1     = (const float*)d_in[6];
    const float* w2     = (const float*)d_in[7];
    const float* a_in2  = (const float*)d_in[8];
    const float* a_out2 = (const float*)d_in[9];
    const float* b2     = (const float*)d_in[10];

    const int N = in_sizes[0] / 128;               // 100000

    // ws: hid2 bf16 (25.6MB) | s_in1 | s_out1 | s_in2 | s_out2 | wT1f | wT2f
    unsigned short* hid2  = (unsigned short*)d_ws;
    float*          s_in1 = (float*)(hid2 + (size_t)N * 128);
    float*          s_out1= s_in1 + N;
    float*          s_in2 = s_out1 + N;
    float*          s_out2= s_in2 + N;
    unsigned short* wT1f  = (unsigned short*)(s_out2 + N);
    unsigned short* wT2f  = wT1f + 128 * 128;
    // hid_L1 (bf16) lives in the upper half of the fp32 d_out;
    // the final aggregate overwrites d_out only after hid_L1 is dead.
    unsigned short* hid1  = (unsigned short*)d_out + out_size;

    dim3 blk(256);
    dim3 ggrid((N + 63) / 64);                     // 1563

    prep_wT_frag<<<64, 64, 0, stream>>>(w1, w2, wT1f, wT2f);

    gemm_score_mfma<<<ggrid, blk, 0, stream>>>(x, wT1f, a_in1, a_out1,
                                               hid1, s_in1, s_out1, N);
    fused_agg_gemm<<<ggrid, blk, 0, stream>>>(hid1, s_in1, s_out1, dst, adj, b1,
                                              wT2f, a_in2, a_out2,
                                              hid2, s_in2, s_out2, N);
    gat_aggregate_final<<<ggrid, blk, 0, stream>>>(hid2, s_in2, s_out2, dst, adj,
                                                   b2, (float*)d_out, N);
}

// Round 3
// 341.659 us; speedup vs baseline: 1.5403x; 1.5403x over previous
//
#include <hip/hip_runtime.h>

#define ALPHA 0.2f
#define LDA 136   // LDS row stride in shorts (272 B: aligned, conflict-balanced)

typedef short bf16x8 __attribute__((ext_vector_type(8)));
typedef float f32x4  __attribute__((ext_vector_type(4)));

static __device__ __forceinline__ float bf2f(unsigned short u) {
    union { unsigned int i; float f; } v; v.i = ((unsigned int)u) << 16; return v.f;
}
static __device__ __forceinline__ unsigned short f2bf(float f) {
    union { float f; unsigned int i; } v; v.f = f;
    unsigned int x = v.i;
    return (unsigned short)((x + 0x7fffu + ((x >> 16) & 1u)) >> 16);  // RNE
}
// bf16 pair unpack: low short = <<16, high short = mask (1 VALU op each)
static __device__ __forceinline__ float bflo(int u) {
    union { unsigned int i; float f; } v; v.i = ((unsigned int)u) << 16; return v.f;
}
static __device__ __forceinline__ float bfhi(int u) {
    union { unsigned int i; float f; } v; v.i = ((unsigned int)u) & 0xffff0000u; return v.f;
}
// 8-channel FMA from one dwordx4 of bf16
static __device__ __forceinline__ void acc8(float* a, const int4 hv, const float w) {
    a[0] = fmaf(w, bflo(hv.x), a[0]); a[1] = fmaf(w, bfhi(hv.x), a[1]);
    a[2] = fmaf(w, bflo(hv.y), a[2]); a[3] = fmaf(w, bfhi(hv.y), a[3]);
    a[4] = fmaf(w, bflo(hv.z), a[4]); a[5] = fmaf(w, bfhi(hv.z), a[5]);
    a[6] = fmaf(w, bflo(hv.w), a[6]); a[7] = fmaf(w, bfhi(hv.w), a[7]);
}

// W in MFMA-FRAGMENT order: unit u16b[(t*4+ks)*64 + lane] = 8 bf16 of
// wT row (t*16 + m), cols (ks*32 + q*8 .. +7), lane = q*16 + m.
__global__ __launch_bounds__(64)
void prep_wT_frag(const float* __restrict__ w1, const float* __restrict__ w2,
                  unsigned short* __restrict__ wT1f, unsigned short* __restrict__ wT2f)
{
    const int b = blockIdx.x;          // 0..63
    const float* w = (b >> 5) ? w2 : w1;
    unsigned short* wf = (b >> 5) ? wT2f : wT1f;
    const int u = b & 31;              // t*4 + ks
    const int t = u >> 2, ks = u & 3;
    const int lane = threadIdx.x;      // 0..63
    const int m = lane & 15, q = lane >> 4;
    const int c  = t * 16 + m;         // output column
    const int k0 = ks * 32 + q * 8;    // input-dim offset

    ushort4 u0, u1;
    u0.x = f2bf(w[(k0 + 0) * 128 + c]); u0.y = f2bf(w[(k0 + 1) * 128 + c]);
    u0.z = f2bf(w[(k0 + 2) * 128 + c]); u0.w = f2bf(w[(k0 + 3) * 128 + c]);
    u1.x = f2bf(w[(k0 + 4) * 128 + c]); u1.y = f2bf(w[(k0 + 5) * 128 + c]);
    u1.z = f2bf(w[(k0 + 6) * 128 + c]); u1.w = f2bf(w[(k0 + 7) * 128 + c]);
    *(ushort4*)&wf[(u * 64 + lane) * 8]     = u0;
    *(ushort4*)&wf[(u * 64 + lane) * 8 + 4] = u1;
}

// Layer-1 GEMM + fused score dots. B direct-from-global (fragment layout).
// min-waves 4: register budget 128, natural codegen (no spill).
__global__ __launch_bounds__(256, 4)
void gemm_score_mfma(const float* __restrict__ src,      // x, fp32
                     const unsigned short* __restrict__ wTf,
                     const float* __restrict__ a_in,
                     const float* __restrict__ a_out,
                     unsigned short* __restrict__ hid,
                     float* __restrict__ s_in,
                     float* __restrict__ s_out,
                     int n)
{
    __shared__ short Es[64 * LDA];    // epilogue staging only
    __shared__ float aS[2][128];

    const int tid  = threadIdx.x;
    const int lane = tid & 63;
    const int wv   = tid >> 6;
    const int m    = lane & 15;
    const int q    = lane >> 4;
    const int rbase = blockIdx.x * 64;
    const int row   = rbase + wv * 16 + m;
    const bool rok  = (row < n);

    if (tid < 128) { aS[0][tid] = a_in[tid]; aS[1][tid] = a_out[tid]; }

    bf16x8 aF[4];
    {
        const float* p = &src[(size_t)row * 128 + q * 8];
        #pragma unroll
        for (int ks = 0; ks < 4; ks++) {
            if (rok) {
                float4 v0 = *(const float4*)(p + ks * 32);
                float4 v1 = *(const float4*)(p + ks * 32 + 4);
                bf16x8 a;
                a[0] = (short)f2bf(v0.x); a[1] = (short)f2bf(v0.y);
                a[2] = (short)f2bf(v0.z); a[3] = (short)f2bf(v0.w);
                a[4] = (short)f2bf(v1.x); a[5] = (short)f2bf(v1.y);
                a[6] = (short)f2bf(v1.z); a[7] = (short)f2bf(v1.w);
                aF[ks] = a;
            } else aF[ks] = (bf16x8){0,0,0,0,0,0,0,0};
        }
    }
    __syncthreads();                  // aS visible to all waves

    f32x4 acc[8];
    #pragma unroll
    for (int t = 0; t < 8; t++) acc[t] = (f32x4){0.f, 0.f, 0.f, 0.f};

    const bf16x8* Bf = (const bf16x8*)wTf;
    #pragma unroll
    for (int ks = 0; ks < 4; ks++) {
        #pragma unroll
        for (int t = 0; t < 8; t++) {
            bf16x8 bF = Bf[(t * 4 + ks) * 64 + lane];
            acc[t] = __builtin_amdgcn_mfma_f32_16x16x32_bf16(aF[ks], bF, acc[t], 0, 0, 0);
        }
    }

    float pin[4] = {0.f, 0.f, 0.f, 0.f}, pout[4] = {0.f, 0.f, 0.f, 0.f};
    #pragma unroll
    for (int t = 0; t < 8; t++) {
        float ai = aS[0][t * 16 + m];
        float ao = aS[1][t * 16 + m];
        #pragma unroll
        for (int r = 0; r < 4; r++) {
            pin[r]  += acc[t][r] * ai;
            pout[r] += acc[t][r] * ao;
        }
    }
    #pragma unroll
    for (int msk = 8; msk >= 1; msk >>= 1) {
        #pragma unroll
        for (int r = 0; r < 4; r++) {
            pin[r]  += __shfl_xor(pin[r],  msk);
            pout[r] += __shfl_xor(pout[r], msk);
        }
    }
    if (m == 0) {
        #pragma unroll
        for (int r = 0; r < 4; r++) {
            int g = rbase + wv * 16 + q * 4 + r;
            if (g < n) { s_in[g] = pin[r]; s_out[g] = pout[r]; }
        }
    }

    // epilogue: per-wave rows, no pre-barrier needed (Es untouched so far)
    #pragma unroll
    for (int t = 0; t < 8; t++)
        #pragma unroll
        for (int r = 0; r < 4; r++)
            Es[(wv * 16 + q * 4 + r) * LDA + t * 16 + m] = (short)f2bf(acc[t][r]);
    __syncthreads();
    #pragma unroll
    for (int i = 0; i < 4; i++) {
        int e = tid + i * 256;
        int r = e >> 4, j = (e & 15) * 8;
        int gr = rbase + r;
        if (gr < n) {
            int4 v = *(const int4*)&Es[r * LDA + j];
            *(int4*)&hid[(size_t)gr * 128 + j] = v;
        }
    }
}

// FUSED aggregate(layer1) + GEMM(layer2). B direct-from-global.
// Phase A2 gather: two rows per 16-lane group processed simultaneously with
// an explicit 4-wide x 2-stage load pipeline (up to 8 dwordx4 row-loads in
// flight per lane) -> ~2x memory-level parallelism vs compiler's natural ~4.
__global__ __launch_bounds__(256, 4)
void fused_agg_gemm(const unsigned short* __restrict__ hid1,
                    const float* __restrict__ s_in1,
                    const float* __restrict__ s_out1,
                    const int* __restrict__ dst,
                    const float* __restrict__ adj,
                    const float* __restrict__ bias1,
                    const unsigned short* __restrict__ wT2f,
                    const float* __restrict__ a_in2,
                    const float* __restrict__ a_out2,
                    unsigned short* __restrict__ hid2,
                    float* __restrict__ s_in2,
                    float* __restrict__ s_out2,
                    int n)
{
    __shared__ short As[64 * LDA];    // pair table -> h1' tile -> epilogue
    __shared__ float aS[2][128];

    const int tid  = threadIdx.x;
    const int lane = tid & 63;
    const int wv   = tid >> 6;
    const int rbase = blockIdx.x * 64;

    if (tid < 128) { aS[0][tid] = a_in2[tid]; aS[1][tid] = a_out2[tid]; }

    // ---- Phase A1: softmax, 4 lanes/node ----
    const int jn  = lane >> 2;
    const int kq  = lane & 3;
    const int node = rbase + wv * 16 + jn;
    const bool nok = (node < n);

    int4   dk4 = make_int4(0, 0, 0, 0);
    float4 av4 = make_float4(0.f, 0.f, 0.f, 0.f);
    float  si  = 0.f;
    if (nok) {
        dk4 = *(const int4*)&dst[node * 16 + kq * 4];
        av4 = *(const float4*)&adj[node * 16 + kq * 4];
        si  = s_in1[node];
    }
    float e0 = si + s_out1[dk4.x], e1 = si + s_out1[dk4.y];
    float e2 = si + s_out1[dk4.z], e3 = si + s_out1[dk4.w];
    e0 = (e0 > 0.f) ? e0 : ALPHA * e0;  e1 = (e1 > 0.f) ? e1 : ALPHA * e1;
    e2 = (e2 > 0.f) ? e2 : ALPHA * e2;  e3 = (e3 > 0.f) ? e3 : ALPHA * e3;
    float mx = fmaxf(fmaxf(e0, e1), fmaxf(e2, e3));
    mx = fmaxf(mx, __shfl_xor(mx, 1));
    mx = fmaxf(mx, __shfl_xor(mx, 2));
    float p0 = __expf(e0 - mx), p1 = __expf(e1 - mx);
    float p2 = __expf(e2 - mx), p3 = __expf(e3 - mx);
    float sm = p0 + p1 + p2 + p3;
    sm += __shfl_xor(sm, 1);
    sm += __shfl_xor(sm, 2);
    const float inv = __frcp_rn(sm);

    // pair table {dk, wk} into bytes [0,128) of this node's As row
    {
        short* rowp = &As[(wv * 16 + jn) * LDA];
        int4 pa = make_int4(dk4.x, __float_as_int(av4.x * p0 * inv),
                            dk4.y, __float_as_int(av4.y * p1 * inv));
        int4 pb = make_int4(dk4.z, __float_as_int(av4.z * p2 * inv),
                            dk4.w, __float_as_int(av4.w * p3 * inv));
        *(int4*)(rowp + kq * 16)     = pa;   // pairs kq*4, kq*4+1
        *(int4*)(rowp + kq * 16 + 8) = pb;   // pairs kq*4+2, kq*4+3
    }

    // ---- Phase A2: paired-row pipelined gather ----
    const int m = lane & 15;
    const int q = lane >> 4;
    {
        const float4 bb0 = *(const float4*)&bias1[m * 8];
        const float4 bb1 = *(const float4*)&bias1[m * 8 + 4];
        #pragma unroll
        for (int jp = 0; jp < 2; jp++) {
            const int rA = wv * 16 + (jp * 2) * 4 + q;    // this group's rows
            const int rB = rA + 4;
            const short* tArow = &As[rA * LDA];
            const short* tBrow = &As[rB * LDA];
            float aA[8] = {0.f,0.f,0.f,0.f,0.f,0.f,0.f,0.f};
            float aB[8] = {0.f,0.f,0.f,0.f,0.f,0.f,0.f,0.f};

            int4 PA = *(const int4*)(tArow);
            int4 PB = *(const int4*)(tBrow);
            int4 HA0 = *(const int4*)&hid1[((size_t)(unsigned)PA.x << 7) + (m << 3)];
            int4 HA1 = *(const int4*)&hid1[((size_t)(unsigned)PA.z << 7) + (m << 3)];
            int4 HB0 = *(const int4*)&hid1[((size_t)(unsigned)PB.x << 7) + (m << 3)];
            int4 HB1 = *(const int4*)&hid1[((size_t)(unsigned)PB.z << 7) + (m << 3)];
            float wA0 = __int_as_float(PA.y), wA1 = __int_as_float(PA.w);
            float wB0 = __int_as_float(PB.y), wB1 = __int_as_float(PB.w);

            #pragma unroll
            for (int k2 = 1; k2 < 8; k2++) {
                int4 nPA = *(const int4*)(tArow + k2 * 8);
                int4 nPB = *(const int4*)(tBrow + k2 * 8);
                int4 nHA0 = *(const int4*)&hid1[((size_t)(unsigned)nPA.x << 7) + (m << 3)];
                int4 nHA1 = *(const int4*)&hid1[((size_t)(unsigned)nPA.z << 7) + (m << 3)];
                int4 nHB0 = *(const int4*)&hid1[((size_t)(unsigned)nPB.x << 7) + (m << 3)];
                int4 nHB1 = *(const int4*)&hid1[((size_t)(unsigned)nPB.z << 7) + (m << 3)];
                acc8(aA, HA0, wA0); acc8(aA, HA1, wA1);
                acc8(aB, HB0, wB0); acc8(aB, HB1, wB1);
                HA0 = nHA0; wA0 = __int_as_float(nPA.y);
                HA1 = nHA1; wA1 = __int_as_float(nPA.w);
                HB0 = nHB0; wB0 = __int_as_float(nPB.y);
                HB1 = nHB1; wB1 = __int_as_float(nPB.w);
            }
            acc8(aA, HA0, wA0); acc8(aA, HA1, wA1);
            acc8(aB, HB0, wB0); acc8(aB, HB1, wB1);

            int4 ovA, ovB;
            ovA.x = (int)f2bf(fmaxf(aA[0]+bb0.x,0.f)) | ((int)f2bf(fmaxf(aA[1]+bb0.y,0.f)) << 16);
            ovA.y = (int)f2bf(fmaxf(aA[2]+bb0.z,0.f)) | ((int)f2bf(fmaxf(aA[3]+bb0.w,0.f)) << 16);
            ovA.z = (int)f2bf(fmaxf(aA[4]+bb1.x,0.f)) | ((int)f2bf(fmaxf(aA[5]+bb1.y,0.f)) << 16);
            ovA.w = (int)f2bf(fmaxf(aA[6]+bb1.z,0.f)) | ((int)f2bf(fmaxf(aA[7]+bb1.w,0.f)) << 16);
            ovB.x = (int)f2bf(fmaxf(aB[0]+bb0.x,0.f)) | ((int)f2bf(fmaxf(aB[1]+bb0.y,0.f)) << 16);
            ovB.y = (int)f2bf(fmaxf(aB[2]+bb0.z,0.f)) | ((int)f2bf(fmaxf(aB[3]+bb0.w,0.f)) << 16);
            ovB.z = (int)f2bf(fmaxf(aB[4]+bb1.x,0.f)) | ((int)f2bf(fmaxf(aB[5]+bb1.y,0.f)) << 16);
            ovB.w = (int)f2bf(fmaxf(aB[6]+bb1.z,0.f)) | ((int)f2bf(fmaxf(aB[7]+bb1.w,0.f)) << 16);
            // overwrites own rows' tables: tables fully consumed above; same-wave order
            *(int4*)&As[rA * LDA + m * 8] = ovA;
            *(int4*)&As[rB * LDA + m * 8] = ovB;
        }
    }
    __syncthreads();    // aS visible; As tile complete (A-frags read next)

    // ---- Phase B: GEMM from As x global-fragment B, single pass ----
    bf16x8 aF[4];
    {
        const short* Abase = &As[(wv * 16 + m) * LDA + q * 8];
        #pragma unroll
        for (int ks = 0; ks < 4; ks++)
            aF[ks] = *(const bf16x8*)(Abase + ks * 32);
    }

    f32x4 acc[8];
    #pragma unroll
    for (int t = 0; t < 8; t++) acc[t] = (f32x4){0.f, 0.f, 0.f, 0.f};

    const bf16x8* Bf = (const bf16x8*)wT2f;
    #pragma unroll
    for (int ks = 0; ks < 4; ks++) {
        #pragma unroll
        for (int t = 0; t < 8; t++) {
            bf16x8 bF = Bf[(t * 4 + ks) * 64 + lane];
            acc[t] = __builtin_amdgcn_mfma_f32_16x16x32_bf16(aF[ks], bF, acc[t], 0, 0, 0);
        }
    }

    // fused layer-2 score dots
    float pin[4] = {0.f, 0.f, 0.f, 0.f}, pout[4] = {0.f, 0.f, 0.f, 0.f};
    #pragma unroll
    for (int t = 0; t < 8; t++) {
        float ai = aS[0][t * 16 + m];
        float ao = aS[1][t * 16 + m];
        #pragma unroll
        for (int r = 0; r < 4; r++) {
            pin[r]  += acc[t][r] * ai;
            pout[r] += acc[t][r] * ao;
        }
    }
    #pragma unroll
    for (int msk = 8; msk >= 1; msk >>= 1) {
        #pragma unroll
        for (int r = 0; r < 4; r++) {
            pin[r]  += __shfl_xor(pin[r],  msk);
            pout[r] += __shfl_xor(pout[r], msk);
        }
    }
    if (m == 0) {
        #pragma unroll
        for (int r = 0; r < 4; r++) {
            int g = rbase + wv * 16 + q * 4 + r;
            if (g < n) { s_in2[g] = pin[r]; s_out2[g] = pout[r]; }
        }
    }

    // epilogue: own-wave rows of As (aF hoisted -> As dead for this wave)
    short* Eo = As;
    #pragma unroll
    for (int t = 0; t < 8; t++)
        #pragma unroll
        for (int r = 0; r < 4; r++)
            Eo[(wv * 16 + q * 4 + r) * LDA + t * 16 + m] = (short)f2bf(acc[t][r]);
    __syncthreads();
    #pragma unroll
    for (int i = 0; i < 4; i++) {
        int e = tid + i * 256;
        int r = e >> 4, j = (e & 15) * 8;
        int gr = rbase + r;
        if (gr < n) {
            int4 v = *(const int4*)&Eo[r * LDA + j];
            *(int4*)&hid2[(size_t)gr * 128 + j] = v;
        }
    }
}

// Final aggregate: same paired-row pipelined gather; fp32 float4 output.
__global__ __launch_bounds__(256, 4)
void gat_aggregate_final(const unsigned short* __restrict__ hid,
                         const float* __restrict__ s_in,
                         const float* __restrict__ s_out,
                         const int* __restrict__ dst,
                         const float* __restrict__ adj,
                         const float* __restrict__ bias,
                         float* __restrict__ out,
                         int n)
{
    __shared__ __align__(16) int2 tbl[64][18];   // 9216 B; stride 144 B

    const int tid  = threadIdx.x;
    const int lane = tid & 63;
    const int wv   = tid >> 6;
    const int rbase = blockIdx.x * 64;

    const int jn  = lane >> 2;
    const int kq  = lane & 3;
    const int node = rbase + wv * 16 + jn;
    const bool nok = (node < n);

    int4   dk4 = make_int4(0, 0, 0, 0);
    float4 av4 = make_float4(0.f, 0.f, 0.f, 0.f);
    float  si  = 0.f;
    if (nok) {
        dk4 = *(const int4*)&dst[node * 16 + kq * 4];
        av4 = *(const float4*)&adj[node * 16 + kq * 4];
        si  = s_in[node];
    }
    float e0 = si + s_out[dk4.x], e1 = si + s_out[dk4.y];
    float e2 = si + s_out[dk4.z], e3 = si + s_out[dk4.w];
    e0 = (e0 > 0.f) ? e0 : ALPHA * e0;  e1 = (e1 > 0.f) ? e1 : ALPHA * e1;
    e2 = (e2 > 0.f) ? e2 : ALPHA * e2;  e3 = (e3 > 0.f) ? e3 : ALPHA * e3;
    float mx = fmaxf(fmaxf(e0, e1), fmaxf(e2, e3));
    mx = fmaxf(mx, __shfl_xor(mx, 1));
    mx = fmaxf(mx, __shfl_xor(mx, 2));
    float p0 = __expf(e0 - mx), p1 = __expf(e1 - mx);
    float p2 = __expf(e2 - mx), p3 = __expf(e3 - mx);
    float sm = p0 + p1 + p2 + p3;
    sm += __shfl_xor(sm, 1);
    sm += __shfl_xor(sm, 2);
    const float inv = __frcp_rn(sm);

    {
        int4 pa = make_int4(dk4.x, __float_as_int(av4.x * p0 * inv),
                            dk4.y, __float_as_int(av4.y * p1 * inv));
        int4 pb = make_int4(dk4.z, __float_as_int(av4.z * p2 * inv),
                            dk4.w, __float_as_int(av4.w * p3 * inv));
        *(int4*)&tbl[wv * 16 + jn][kq * 4]     = pa;
        *(int4*)&tbl[wv * 16 + jn][kq * 4 + 2] = pb;
    }
    // table rows [wv*16, wv*16+16) written and read by the same wave: no barrier

    const int m = lane & 15;
    const int q = lane >> 4;
    const float4 bb0 = *(const float4*)&bias[m * 8];
    const float4 bb1 = *(const float4*)&bias[m * 8 + 4];

    #pragma unroll
    for (int jp = 0; jp < 2; jp++) {
        const int rA = wv * 16 + (jp * 2) * 4 + q;
        const int rB = rA + 4;
        const int4* tA = (const int4*)&tbl[rA][0];
        const int4* tB = (const int4*)&tbl[rB][0];
        float aA[8] = {0.f,0.f,0.f,0.f,0.f,0.f,0.f,0.f};
        float aB[8] = {0.f,0.f,0.f,0.f,0.f,0.f,0.f,0.f};

        int4 PA = tA[0];
        int4 PB = tB[0];
        int4 HA0 = *(const int4*)&hid[((size_t)(unsigned)PA.x << 7) + (m << 3)];
        int4 HA1 = *(const int4*)&hid[((size_t)(unsigned)PA.z << 7) + (m << 3)];
        int4 HB0 = *(const int4*)&hid[((size_t)(unsigned)PB.x << 7) + (m << 3)];
        int4 HB1 = *(const int4*)&hid[((size_t)(unsigned)PB.z << 7) + (m << 3)];
        float wA0 = __int_as_float(PA.y), wA1 = __int_as_float(PA.w);
        float wB0 = __int_as_float(PB.y), wB1 = __int_as_float(PB.w);

        #pragma unroll
        for (int k2 = 1; k2 < 8; k2++) {
            int4 nPA = tA[k2];
            int4 nPB = tB[k2];
            int4 nHA0 = *(const int4*)&hid[((size_t)(unsigned)nPA.x << 7) + (m << 3)];
            int4 nHA1 = *(const int4*)&hid[((size_t)(unsigned)nPA.z << 7) + (m << 3)];
            int4 nHB0 = *(const int4*)&hid[((size_t)(unsigned)nPB.x << 7) + (m << 3)];
            int4 nHB1 = *(const int4*)&hid[((size_t)(unsigned)nPB.z << 7) + (m << 3)];
            acc8(aA, HA0, wA0); acc8(aA, HA1, wA1);
            acc8(aB, HB0, wB0); acc8(aB, HB1, wB1);
            HA0 = nHA0; wA0 = __int_as_float(nPA.y);
            HA1 = nHA1; wA1 = __int_as_float(nPA.w);
            HB0 = nHB0; wB0 = __int_as_float(nPB.y);
            HB1 = nHB1; wB1 = __int_as_float(nPB.w);
        }
        acc8(aA, HA0, wA0); acc8(aA, HA1, wA1);
        acc8(aB, HB0, wB0); acc8(aB, HB1, wB1);

        const int nA = rbase + rA;
        const int nB = rbase + rB;
        if (nA < n) {
            float4 o0, o1;
            o0.x = fmaxf(aA[0] + bb0.x, 0.f); o0.y = fmaxf(aA[1] + bb0.y, 0.f);
            o0.z = fmaxf(aA[2] + bb0.z, 0.f); o0.w = fmaxf(aA[3] + bb0.w, 0.f);
            o1.x = fmaxf(aA[4] + bb1.x, 0.f); o1.y = fmaxf(aA[5] + bb1.y, 0.f);
            o1.z = fmaxf(aA[6] + bb1.z, 0.f); o1.w = fmaxf(aA[7] + bb1.w, 0.f);
            float* op = &out[(size_t)nA * 128 + m * 8];
            *(float4*)op       = o0;
            *(float4*)(op + 4) = o1;
        }
        if (nB < n) {
            float4 o0, o1;
            o0.x = fmaxf(aB[0] + bb0.x, 0.f); o0.y = fmaxf(aB[1] + bb0.y, 0.f);
            o0.z = fmaxf(aB[2] + bb0.z, 0.f); o0.w = fmaxf(aB[3] + bb0.w, 0.f);
            o1.x = fmaxf(aB[4] + bb1.x, 0.f); o1.y = fmaxf(aB[5] + bb1.y, 0.f);
            o1.z = fmaxf(aB[6] + bb1.z, 0.f); o1.w = fmaxf(aB[7] + bb1.w, 0.f);
            float* op = &out[(size_t)nB * 128 + m * 8];
            *(float4*)op       = o0;
            *(float4*)(op + 4) = o1;
        }
    }
}

extern "C" void kernel_launch(void* const* d_in, const int* in_sizes, int n_in,
                              void* d_out, int out_size, void* d_ws, size_t ws_size,
                              hipStream_t stream)
{
    const float* x      = (const float*)d_in[0];
    const int*   dst    = (const int*)d_in[1];
    const float* adj    = (const float*)d_in[2];
    const float* w1     = (const float*)d_in[3];
    const float* a_in1  = (const float*)d_in[4];
    const float* a_out1 = (const float*)d_in[5];
    const float* b1     = (const float*)d_in[6];
    const float* w2     = (const float*)d_in[7];
    const float* a_in2  = (const float*)d_in[8];
    const float* a_out2 = (const float*)d_in[9];
    const float* b2     = (const float*)d_in[10];

    const int N = in_sizes[0] / 128;               // 100000

    // ws: hid2 bf16 (25.6MB) | s_in1 | s_out1 | s_in2 | s_out2 | wT1f | wT2f
    unsigned short* hid2  = (unsigned short*)d_ws;
    float*          s_in1 = (float*)(hid2 + (size_t)N * 128);
    float*          s_out1= s_in1 + N;
    float*          s_in2 = s_out1 + N;
    float*          s_out2= s_in2 + N;
    unsigned short* wT1f  = (unsigned short*)(s_out2 + N);
    unsigned short* wT2f  = wT1f + 128 * 128;
    // hid_L1 (bf16) lives in the upper half of the fp32 d_out;
    // the final aggregate overwrites d_out only after hid_L1 is dead.
    unsigned short* hid1  = (unsigned short*)d_out + out_size;

    dim3 blk(256);
    dim3 ggrid((N + 63) / 64);                     // 1563

    prep_wT_frag<<<64, 64, 0, stream>>>(w1, w2, wT1f, wT2f);

    gemm_score_mfma<<<ggrid, blk, 0, stream>>>(x, wT1f, a_in1, a_out1,
                                               hid1, s_in1, s_out1, N);
    fused_agg_gemm<<<ggrid, blk, 0, stream>>>(hid1, s_in1, s_out1, dst, adj, b1,
                                              wT2f, a_in2, a_out2,
                                              hid2, s_in2, s_out2, N);
    gat_aggregate_final<<<ggrid, blk, 0, stream>>>(hid2, s_in2, s_out2, dst, adj,
                                                   b2, (float*)d_out, N);
}

// Round 4
// 254.395 us; speedup vs baseline: 2.0687x; 1.3430x over previous
//
#include <hip/hip_runtime.h>

#define ALPHA 0.2f
#define LDA 136   // LDS row stride in shorts (272 B: aligned, conflict-balanced)

typedef short bf16x8 __attribute__((ext_vector_type(8)));
typedef float f32x4  __attribute__((ext_vector_type(4)));

static __device__ __forceinline__ float bf2f(unsigned short u) {
    union { unsigned int i; float f; } v; v.i = ((unsigned int)u) << 16; return v.f;
}
static __device__ __forceinline__ unsigned short f2bf(float f) {
    union { float f; unsigned int i; } v; v.f = f;
    unsigned int x = v.i;
    return (unsigned short)((x + 0x7fffu + ((x >> 16) & 1u)) >> 16);  // RNE
}
// bf16 pair unpack: low short = <<16, high short = mask (1 VALU op each)
static __device__ __forceinline__ float bflo(int u) {
    union { unsigned int i; float f; } v; v.i = ((unsigned int)u) << 16; return v.f;
}
static __device__ __forceinline__ float bfhi(int u) {
    union { unsigned int i; float f; } v; v.i = ((unsigned int)u) & 0xffff0000u; return v.f;
}

// 8-channel accumulate into NAMED scalars (no arrays -> no SROA hazard)
#define ACCW(g, wf) do { \
    a0 = fmaf((wf), bflo((g).x), a0); a1 = fmaf((wf), bfhi((g).x), a1); \
    a2 = fmaf((wf), bflo((g).y), a2); a3 = fmaf((wf), bfhi((g).y), a3); \
    a4 = fmaf((wf), bflo((g).z), a4); a5 = fmaf((wf), bfhi((g).z), a5); \
    a6 = fmaf((wf), bflo((g).w), a6); a7 = fmaf((wf), bfhi((g).w), a7); } while (0)

// wT[c][k] = bf16(w[k][c]).  32 blocks x 128 thr (parallel, ~2 us).
__global__ __launch_bounds__(128)
void prep_wT_kernel(const float* __restrict__ w1, const float* __restrict__ w2,
                    unsigned short* __restrict__ wT1, unsigned short* __restrict__ wT2)
{
    const int b = blockIdx.x;
    const float* w = (b >> 4) ? w2 : w1;
    unsigned short* wT = (b >> 4) ? wT2 : wT1;
    const int k0 = (b & 15) * 8;
    const int c = threadIdx.x;          // 0..127

    ushort4 u0, u1;
    u0.x = f2bf(w[(k0 + 0) * 128 + c]); u0.y = f2bf(w[(k0 + 1) * 128 + c]);
    u0.z = f2bf(w[(k0 + 2) * 128 + c]); u0.w = f2bf(w[(k0 + 3) * 128 + c]);
    u1.x = f2bf(w[(k0 + 4) * 128 + c]); u1.y = f2bf(w[(k0 + 5) * 128 + c]);
    u1.z = f2bf(w[(k0 + 6) * 128 + c]); u1.w = f2bf(w[(k0 + 7) * 128 + c]);
    *(ushort4*)&wT[c * 128 + k0]     = u0;
    *(ushort4*)&wT[c * 128 + k0 + 4] = u1;
}

// Layer-1 GEMM + fused score dots (round-1 structure, verified 27 us).
__global__ __launch_bounds__(256, 4)
void gemm_score_mfma(const float* __restrict__ src,      // x, fp32
                     const unsigned short* __restrict__ wT,
                     const float* __restrict__ a_in,
                     const float* __restrict__ a_out,
                     unsigned short* __restrict__ hid,
                     float* __restrict__ s_in,
                     float* __restrict__ s_out,
                     int n)
{
    __shared__ short Bs[128 * LDA];   // 34816 B (epilogue reuses first half)
    __shared__ float aS[2][128];

    const int tid  = threadIdx.x;
    const int lane = tid & 63;
    const int wv   = tid >> 6;
    const int m    = lane & 15;
    const int q    = lane >> 4;
    const int rbase = blockIdx.x * 64;
    const int row   = rbase + wv * 16 + m;
    const bool rok  = (row < n);

    if (tid < 128) { aS[0][tid] = a_in[tid]; aS[1][tid] = a_out[tid]; }

    bf16x8 aF[4];
    {
        const float* p = &src[(size_t)row * 128 + q * 8];
        #pragma unroll
        for (int ks = 0; ks < 4; ks++) {
            if (rok) {
                float4 v0 = *(const float4*)(p + ks * 32);
                float4 v1 = *(const float4*)(p + ks * 32 + 4);
                bf16x8 a;
                a[0] = (short)f2bf(v0.x); a[1] = (short)f2bf(v0.y);
                a[2] = (short)f2bf(v0.z); a[3] = (short)f2bf(v0.w);
                a[4] = (short)f2bf(v1.x); a[5] = (short)f2bf(v1.y);
                a[6] = (short)f2bf(v1.z); a[7] = (short)f2bf(v1.w);
                aF[ks] = a;
            } else aF[ks] = (bf16x8){0,0,0,0,0,0,0,0};
        }
    }

    #pragma unroll
    for (int i = 0; i < 8; i++) {
        int e = tid + i * 256;
        int nr = e >> 4, j = (e & 15) * 8;
        int4 v = *(const int4*)&wT[nr * 128 + j];
        *(int4*)&Bs[nr * LDA + j] = v;
    }
    __syncthreads();

    f32x4 acc[8];
    #pragma unroll
    for (int t = 0; t < 8; t++) acc[t] = (f32x4){0.f, 0.f, 0.f, 0.f};

    const short* Bbase = &Bs[m * LDA + q * 8];
    #pragma unroll
    for (int ks = 0; ks < 4; ks++) {
        #pragma unroll
        for (int t = 0; t < 8; t++) {
            bf16x8 bF = *(const bf16x8*)(Bbase + t * 16 * LDA + ks * 32);
            acc[t] = __builtin_amdgcn_mfma_f32_16x16x32_bf16(aF[ks], bF, acc[t], 0, 0, 0);
        }
    }

    float pin[4] = {0.f, 0.f, 0.f, 0.f}, pout[4] = {0.f, 0.f, 0.f, 0.f};
    #pragma unroll
    for (int t = 0; t < 8; t++) {
        float ai = aS[0][t * 16 + m];
        float ao = aS[1][t * 16 + m];
        #pragma unroll
        for (int r = 0; r < 4; r++) {
            pin[r]  += acc[t][r] * ai;
            pout[r] += acc[t][r] * ao;
        }
    }
    #pragma unroll
    for (int msk = 8; msk >= 1; msk >>= 1) {
        #pragma unroll
        for (int r = 0; r < 4; r++) {
            pin[r]  += __shfl_xor(pin[r],  msk);
            pout[r] += __shfl_xor(pout[r], msk);
        }
    }
    if (m == 0) {
        #pragma unroll
        for (int r = 0; r < 4; r++) {
            int g = rbase + wv * 16 + q * 4 + r;
            if (g < n) { s_in[g] = pin[r]; s_out[g] = pout[r]; }
        }
    }

    __syncthreads();
    short* Es = Bs;
    #pragma unroll
    for (int t = 0; t < 8; t++)
        #pragma unroll
        for (int r = 0; r < 4; r++)
            Es[(wv * 16 + q * 4 + r) * LDA + t * 16 + m] = (short)f2bf(acc[t][r]);
    __syncthreads();
    #pragma unroll
    for (int i = 0; i < 4; i++) {
        int e = tid + i * 256;
        int r = e >> 4, j = (e & 15) * 8;
        int gr = rbase + r;
        if (gr < n) {
            int4 v = *(const int4*)&Es[r * LDA + j];
            *(int4*)&hid[(size_t)gr * 128 + j] = v;
        }
    }
}

// FUSED aggregate(layer1) + GEMM(layer2), round-1 structure.
// Phase A2 gather rewritten: straight-line SSA batch of 8 named int4 loads
// per row-half (vmcnt depth 8, no consumer interleave), named scalar accs.
__global__ __launch_bounds__(256, 4)
void fused_agg_gemm(const unsigned short* __restrict__ hid1,
                    const float* __restrict__ s_in1,
                    const float* __restrict__ s_out1,
                    const int* __restrict__ dst,
                    const float* __restrict__ adj,
                    const float* __restrict__ bias1,
                    const unsigned short* __restrict__ wT2,
                    const float* __restrict__ a_in2,
                    const float* __restrict__ a_out2,
                    unsigned short* __restrict__ hid2,
                    float* __restrict__ s_in2,
                    float* __restrict__ s_out2,
                    int n)
{
    __shared__ short As[64 * LDA];    // pair table -> h1' tile; epilogue aliases it
    __shared__ short Bs[64 * LDA];    // HALF of wT2 at a time
    __shared__ float aS[2][128];

    const int tid  = threadIdx.x;
    const int lane = tid & 63;
    const int wv   = tid >> 6;
    const int rbase = blockIdx.x * 64;

    if (tid < 128) { aS[0][tid] = a_in2[tid]; aS[1][tid] = a_out2[tid]; }

    // stage Bs pass 1: wT2 rows 0..63 (cols 0..63 of W2)
    #pragma unroll
    for (int i = 0; i < 4; i++) {
        int e = tid + i * 256;                // 1024 int4 units
        int nr = e >> 4, j = (e & 15) * 8;
        int4 v = *(const int4*)&wT2[nr * 128 + j];
        *(int4*)&Bs[nr * LDA + j] = v;
    }

    // ---- Phase A1: softmax, 4 lanes/node ----
    const int jn  = lane >> 2;
    const int kq  = lane & 3;
    const int node = rbase + wv * 16 + jn;
    const bool nok = (node < n);

    int4   dk4 = make_int4(0, 0, 0, 0);
    float4 av4 = make_float4(0.f, 0.f, 0.f, 0.f);
    float  si  = 0.f;
    if (nok) {
        dk4 = *(const int4*)&dst[node * 16 + kq * 4];
        av4 = *(const float4*)&adj[node * 16 + kq * 4];
        si  = s_in1[node];
    }
    float e0 = si + s_out1[dk4.x], e1 = si + s_out1[dk4.y];
    float e2 = si + s_out1[dk4.z], e3 = si + s_out1[dk4.w];
    e0 = (e0 > 0.f) ? e0 : ALPHA * e0;  e1 = (e1 > 0.f) ? e1 : ALPHA * e1;
    e2 = (e2 > 0.f) ? e2 : ALPHA * e2;  e3 = (e3 > 0.f) ? e3 : ALPHA * e3;
    float mx = fmaxf(fmaxf(e0, e1), fmaxf(e2, e3));
    mx = fmaxf(mx, __shfl_xor(mx, 1));
    mx = fmaxf(mx, __shfl_xor(mx, 2));
    float p0 = __expf(e0 - mx), p1 = __expf(e1 - mx);
    float p2 = __expf(e2 - mx), p3 = __expf(e3 - mx);
    float sm = p0 + p1 + p2 + p3;
    sm += __shfl_xor(sm, 1);
    sm += __shfl_xor(sm, 2);
    const float inv = __frcp_rn(sm);

    // pair table {dk, wk} into bytes [0,128) of this node's As row
    {
        short* rowp = &As[(wv * 16 + jn) * LDA];
        int4 pa = make_int4(dk4.x, __float_as_int(av4.x * p0 * inv),
                            dk4.y, __float_as_int(av4.y * p1 * inv));
        int4 pb = make_int4(dk4.z, __float_as_int(av4.z * p2 * inv),
                            dk4.w, __float_as_int(av4.w * p3 * inv));
        *(int4*)(rowp + kq * 16)     = pa;   // pairs kq*4, kq*4+1
        *(int4*)(rowp + kq * 16 + 8) = pb;   // pairs kq*4+2, kq*4+3
    }

    // ---- Phase A2: gather, 16-lane group per node, batch-of-8 loads ----
    const int m = lane & 15;
    const int q = lane >> 4;
    {
        const float4 bb0 = *(const float4*)&bias1[m * 8];
        const float4 bb1 = *(const float4*)&bias1[m * 8 + 4];
        const char* hb = (const char*)hid1 + (m << 4);
        #pragma unroll
        for (int jj = 0; jj < 4; jj++) {
            const int rloc = wv * 16 + jj * 4 + q;   // each (jj,q) owns one row
            const int4* tp = (const int4*)&As[rloc * LDA];   // 8 pair-entries
            float a0 = 0.f, a1 = 0.f, a2 = 0.f, a3 = 0.f;
            float a4 = 0.f, a5 = 0.f, a6 = 0.f, a7 = 0.f;
            #pragma unroll
            for (int h = 0; h < 2; h++) {
                const int4 t0 = tp[h * 4 + 0];
                const int4 t1 = tp[h * 4 + 1];
                const int4 t2 = tp[h * 4 + 2];
                const int4 t3 = tp[h * 4 + 3];
                const int4 g0 = *(const int4*)(hb + ((unsigned)t0.x << 8));
                const int4 g1 = *(const int4*)(hb + ((unsigned)t0.z << 8));
                const int4 g2 = *(const int4*)(hb + ((unsigned)t1.x << 8));
                const int4 g3 = *(const int4*)(hb + ((unsigned)t1.z << 8));
                const int4 g4 = *(const int4*)(hb + ((unsigned)t2.x << 8));
                const int4 g5 = *(const int4*)(hb + ((unsigned)t2.z << 8));
                const int4 g6 = *(const int4*)(hb + ((unsigned)t3.x << 8));
                const int4 g7 = *(const int4*)(hb + ((unsigned)t3.z << 8));
                ACCW(g0, __int_as_float(t0.y)); ACCW(g1, __int_as_float(t0.w));
                ACCW(g2, __int_as_float(t1.y)); ACCW(g3, __int_as_float(t1.w));
                ACCW(g4, __int_as_float(t2.y)); ACCW(g5, __int_as_float(t2.w));
                ACCW(g6, __int_as_float(t3.y)); ACCW(g7, __int_as_float(t3.w));
            }
            int4 ov;
            ov.x = (int)f2bf(fmaxf(a0 + bb0.x, 0.f)) | ((int)f2bf(fmaxf(a1 + bb0.y, 0.f)) << 16);
            ov.y = (int)f2bf(fmaxf(a2 + bb0.z, 0.f)) | ((int)f2bf(fmaxf(a3 + bb0.w, 0.f)) << 16);
            ov.z = (int)f2bf(fmaxf(a4 + bb1.x, 0.f)) | ((int)f2bf(fmaxf(a5 + bb1.y, 0.f)) << 16);
            ov.w = (int)f2bf(fmaxf(a6 + bb1.z, 0.f)) | ((int)f2bf(fmaxf(a7 + bb1.w, 0.f)) << 16);
            *(int4*)&As[rloc * LDA + m * 8] = ov;    // overwrites own table: safe
        }
    }
    __syncthreads();    // aS visible; As tile complete (A-frags read next)

    // ---- Phase B: GEMM from As x Bs, two B passes ----
    bf16x8 aF[4];
    {
        const short* Abase = &As[(wv * 16 + m) * LDA + q * 8];
        #pragma unroll
        for (int ks = 0; ks < 4; ks++)
            aF[ks] = *(const bf16x8*)(Abase + ks * 32);
    }

    f32x4 acc[8];
    #pragma unroll
    for (int t = 0; t < 8; t++) acc[t] = (f32x4){0.f, 0.f, 0.f, 0.f};

    const short* Bbase = &Bs[m * LDA + q * 8];
    #pragma unroll
    for (int ks = 0; ks < 4; ks++) {
        #pragma unroll
        for (int t = 0; t < 4; t++) {       // pass 1: W cols 0..63
            bf16x8 bF = *(const bf16x8*)(Bbase + t * 16 * LDA + ks * 32);
            acc[t] = __builtin_amdgcn_mfma_f32_16x16x32_bf16(aF[ks], bF, acc[t], 0, 0, 0);
        }
    }
    __syncthreads();
    #pragma unroll
    for (int i = 0; i < 4; i++) {           // restage: wT2 rows 64..127
        int e = tid + i * 256;
        int nr = e >> 4, j = (e & 15) * 8;
        int4 v = *(const int4*)&wT2[(64 + nr) * 128 + j];
        *(int4*)&Bs[nr * LDA + j] = v;
    }
    __syncthreads();
    #pragma unroll
    for (int ks = 0; ks < 4; ks++) {
        #pragma unroll
        for (int t = 4; t < 8; t++) {       // pass 2: W cols 64..127
            bf16x8 bF = *(const bf16x8*)(Bbase + (t - 4) * 16 * LDA + ks * 32);
            acc[t] = __builtin_amdgcn_mfma_f32_16x16x32_bf16(aF[ks], bF, acc[t], 0, 0, 0);
        }
    }

    // fused layer-2 score dots
    float pin[4] = {0.f, 0.f, 0.f, 0.f}, pout[4] = {0.f, 0.f, 0.f, 0.f};
    #pragma unroll
    for (int t = 0; t < 8; t++) {
        float ai = aS[0][t * 16 + m];
        float ao = aS[1][t * 16 + m];
        #pragma unroll
        for (int r = 0; r < 4; r++) {
            pin[r]  += acc[t][r] * ai;
            pout[r] += acc[t][r] * ao;
        }
    }
    #pragma unroll
    for (int msk = 8; msk >= 1; msk >>= 1) {
        #pragma unroll
        for (int r = 0; r < 4; r++) {
            pin[r]  += __shfl_xor(pin[r],  msk);
            pout[r] += __shfl_xor(pout[r], msk);
        }
    }
    if (m == 0) {
        #pragma unroll
        for (int r = 0; r < 4; r++) {
            int g = rbase + wv * 16 + q * 4 + r;
            if (g < n) { s_in2[g] = pin[r]; s_out2[g] = pout[r]; }
        }
    }

    __syncthreads();
    short* Eo = As;                          // aF hoisted: As dead
    #pragma unroll
    for (int t = 0; t < 8; t++)
        #pragma unroll
        for (int r = 0; r < 4; r++)
            Eo[(wv * 16 + q * 4 + r) * LDA + t * 16 + m] = (short)f2bf(acc[t][r]);
    __syncthreads();
    #pragma unroll
    for (int i = 0; i < 4; i++) {
        int e = tid + i * 256;
        int r = e >> 4, j = (e & 15) * 8;
        int gr = rbase + r;
        if (gr < n) {
            int4 v = *(const int4*)&Eo[r * LDA + j];
            *(int4*)&hid2[(size_t)gr * 128 + j] = v;
        }
    }
}

// Final aggregate: round-1 structure; gather inner loop rewritten as
// straight-line SSA batch-of-8 named loads (vmcnt depth 8, no arrays).
__global__ __launch_bounds__(256, 4)
void gat_aggregate_final(const unsigned short* __restrict__ hid,
                         const float* __restrict__ s_in,
                         const float* __restrict__ s_out,
                         const int* __restrict__ dst,
                         const float* __restrict__ adj,
                         const float* __restrict__ bias,
                         float* __restrict__ out,
                         int n)
{
    __shared__ __align__(16) int2 tbl[64][18];   // 9216 B; stride 144 B

    const int tid  = threadIdx.x;
    const int lane = tid & 63;
    const int wv   = tid >> 6;
    const int rbase = blockIdx.x * 64;

    const int jn  = lane >> 2;
    const int kq  = lane & 3;
    const int node = rbase + wv * 16 + jn;
    const bool nok = (node < n);

    int4   dk4 = make_int4(0, 0, 0, 0);
    float4 av4 = make_float4(0.f, 0.f, 0.f, 0.f);
    float  si  = 0.f;
    if (nok) {
        dk4 = *(const int4*)&dst[node * 16 + kq * 4];
        av4 = *(const float4*)&adj[node * 16 + kq * 4];
        si  = s_in[node];
    }
    float e0 = si + s_out[dk4.x], e1 = si + s_out[dk4.y];
    float e2 = si + s_out[dk4.z], e3 = si + s_out[dk4.w];
    e0 = (e0 > 0.f) ? e0 : ALPHA * e0;  e1 = (e1 > 0.f) ? e1 : ALPHA * e1;
    e2 = (e2 > 0.f) ? e2 : ALPHA * e2;  e3 = (e3 > 0.f) ? e3 : ALPHA * e3;
    float mx = fmaxf(fmaxf(e0, e1), fmaxf(e2, e3));
    mx = fmaxf(mx, __shfl_xor(mx, 1));
    mx = fmaxf(mx, __shfl_xor(mx, 2));
    float p0 = __expf(e0 - mx), p1 = __expf(e1 - mx);
    float p2 = __expf(e2 - mx), p3 = __expf(e3 - mx);
    float sm = p0 + p1 + p2 + p3;
    sm += __shfl_xor(sm, 1);
    sm += __shfl_xor(sm, 2);
    const float inv = __frcp_rn(sm);

    {
        int4 pa = make_int4(dk4.x, __float_as_int(av4.x * p0 * inv),
                            dk4.y, __float_as_int(av4.y * p1 * inv));
        int4 pb = make_int4(dk4.z, __float_as_int(av4.z * p2 * inv),
                            dk4.w, __float_as_int(av4.w * p3 * inv));
        *(int4*)&tbl[wv * 16 + jn][kq * 4]     = pa;
        *(int4*)&tbl[wv * 16 + jn][kq * 4 + 2] = pb;
    }
    // table rows [wv*16, wv*16+16) written and read by the same wave: no barrier

    const int m = lane & 15;
    const int q = lane >> 4;
    const float4 bb0 = *(const float4*)&bias[m * 8];
    const float4 bb1 = *(const float4*)&bias[m * 8 + 4];
    const char* hb = (const char*)hid + (m << 4);

    #pragma unroll
    for (int jj = 0; jj < 4; jj++) {
        const int rl = wv * 16 + jj * 4 + q;
        const int nodeg = rbase + rl;
        const int4* tp = (const int4*)&tbl[rl][0];   // 8 pair-entries
        float a0 = 0.f, a1 = 0.f, a2 = 0.f, a3 = 0.f;
        float a4 = 0.f, a5 = 0.f, a6 = 0.f, a7 = 0.f;
        #pragma unroll
        for (int h = 0; h < 2; h++) {
            const int4 t0 = tp[h * 4 + 0];
            const int4 t1 = tp[h * 4 + 1];
            const int4 t2 = tp[h * 4 + 2];
            const int4 t3 = tp[h * 4 + 3];
            const int4 g0 = *(const int4*)(hb + ((unsigned)t0.x << 8));
            const int4 g1 = *(const int4*)(hb + ((unsigned)t0.z << 8));
            const int4 g2 = *(const int4*)(hb + ((unsigned)t1.x << 8));
            const int4 g3 = *(const int4*)(hb + ((unsigned)t1.z << 8));
            const int4 g4 = *(const int4*)(hb + ((unsigned)t2.x << 8));
            const int4 g5 = *(const int4*)(hb + ((unsigned)t2.z << 8));
            const int4 g6 = *(const int4*)(hb + ((unsigned)t3.x << 8));
            const int4 g7 = *(const int4*)(hb + ((unsigned)t3.z << 8));
            ACCW(g0, __int_as_float(t0.y)); ACCW(g1, __int_as_float(t0.w));
            ACCW(g2, __int_as_float(t1.y)); ACCW(g3, __int_as_float(t1.w));
            ACCW(g4, __int_as_float(t2.y)); ACCW(g5, __int_as_float(t2.w));
            ACCW(g6, __int_as_float(t3.y)); ACCW(g7, __int_as_float(t3.w));
        }
        if (nodeg < n) {
            float4 o0, o1;
            o0.x = fmaxf(a0 + bb0.x, 0.f); o0.y = fmaxf(a1 + bb0.y, 0.f);
            o0.z = fmaxf(a2 + bb0.z, 0.f); o0.w = fmaxf(a3 + bb0.w, 0.f);
            o1.x = fmaxf(a4 + bb1.x, 0.f); o1.y = fmaxf(a5 + bb1.y, 0.f);
            o1.z = fmaxf(a6 + bb1.z, 0.f); o1.w = fmaxf(a7 + bb1.w, 0.f);
            float* op = &out[(size_t)nodeg * 128 + m * 8];
            *(float4*)op       = o0;
            *(float4*)(op + 4) = o1;
        }
    }
}

extern "C" void kernel_launch(void* const* d_in, const int* in_sizes, int n_in,
                              void* d_out, int out_size, void* d_ws, size_t ws_size,
                              hipStream_t stream)
{
    const float* x      = (const float*)d_in[0];
    const int*   dst    = (const int*)d_in[1];
    const float* adj    = (const float*)d_in[2];
    const float* w1     = (const float*)d_in[3];
    const float* a_in1  = (const float*)d_in[4];
    const float* a_out1 = (const float*)d_in[5];
    const float* b1     = (const float*)d_in[6];
    const float* w2     = (const float*)d_in[7];
    const float* a_in2  = (const float*)d_in[8];
    const float* a_out2 = (const float*)d_in[9];
    const float* b2     = (const float*)d_in[10];

    const int N = in_sizes[0] / 128;               // 100000

    // ws: hid2 bf16 (25.6MB) | s_in1 | s_out1 | s_in2 | s_out2 | wT1 | wT2
    unsigned short* hid2  = (unsigned short*)d_ws;
    float*          s_in1 = (float*)(hid2 + (size_t)N * 128);
    float*          s_out1= s_in1 + N;
    float*          s_in2 = s_out1 + N;
    float*          s_out2= s_in2 + N;
    unsigned short* wT1   = (unsigned short*)(s_out2 + N);
    unsigned short* wT2   = wT1 + 128 * 128;
    // hid_L1 (bf16) lives in the upper half of the fp32 d_out;
    // the final aggregate overwrites d_out only after hid_L1 is dead.
    unsigned short* hid1  = (unsigned short*)d_out + out_size;

    dim3 blk(256);
    dim3 ggrid((N + 63) / 64);                     // 1563

    prep_wT_kernel<<<32, 128, 0, stream>>>(w1, w2, wT1, wT2);

    gemm_score_mfma<<<ggrid, blk, 0, stream>>>(x, wT1, a_in1, a_out1,
                                               hid1, s_in1, s_out1, N);
    fused_agg_gemm<<<ggrid, blk, 0, stream>>>(hid1, s_in1, s_out1, dst, adj, b1,
                                              wT2, a_in2, a_out2,
                                              hid2, s_in2, s_out2, N);
    gat_aggregate_final<<<ggrid, blk, 0, stream>>>(hid2, s_in2, s_out2, dst, adj,
                                                   b2, (float*)d_out, N);
}